// Round 20
// baseline (206.971 us; speedup 1.0000x reference)
//
#include <hip/hip_runtime.h>
#include <hip/hip_bf16.h>

// Problem constants (match reference)
#define B_DIM 8192
#define D_DIM 1024
#define N_DIM 4096
#define TAU_INV 5.0f

typedef __bf16 bf16x8 __attribute__((ext_vector_type(8)));
typedef float  f32x4  __attribute__((ext_vector_type(4)));

// ---------------------------------------------------------------------------
__device__ __forceinline__ void gld_lds16(const void* g, void* l) {
  __builtin_amdgcn_global_load_lds((const __attribute__((address_space(1))) void*)g,
                                   (__attribute__((address_space(3))) void*)l,
                                   16, 0, 0);
}
__device__ __forceinline__ float fast_rcp(float x) {
  return __builtin_amdgcn_rcpf(x);
}
#define MFMA(a, b, c) __builtin_amdgcn_mfma_f32_16x16x32_bf16((a), (b), (c), 0, 0, 0)

// ---------------------------------------------------------------------------
// prep_w: W (f32 [D,N]) -> wht (bf16 [N,D]) transposed
__global__ void prep_w(const float* __restrict__ W, __bf16* __restrict__ wht) {
  __shared__ float tile[32][33];
  const int tn = blockIdx.x & 127;
  const int tk = blockIdx.x >> 7;
  const int tx = threadIdx.x & 31;
  const int ty = threadIdx.x >> 5;
#pragma unroll
  for (int r = 0; r < 4; ++r) {
    const int k = tk * 32 + ty + r * 8;
    tile[ty + r * 8][tx] = W[(size_t)k * N_DIM + tn * 32 + tx];
  }
  __syncthreads();
#pragma unroll
  for (int r = 0; r < 4; ++r) {
    const int nn = tn * 32 + ty + r * 8;
    const int kk = tk * 32 + tx;
    wht[(size_t)nn * D_DIM + kk] = (__bf16)tile[tx][ty + r * 8];
  }
}

// ---------------------------------------------------------------------------
// GEMM kernel (round-15 K-loop verbatim; epilogue = bias + NORMAL out0
// stores only — out0 (134 MB) stays L3-resident for act_kernel's re-read).
// 128x256 tile, BK=32, K=1024 single-term bf16 (absmax floor verified),
// 8 waves (2Mx4N), wave tile 64x64 (acc 64 VGPR, no spill). Single-barrier
// dbuf loop, fused f32->bf16 A staging, B via gld_lds, rotation swizzle
// (measured 0 conflicts), setprio, LDS-transpose store path.
#define BM 128
#define BN 256
#define BK 32
#define THREADS 512

__global__ __launch_bounds__(THREADS, 4) void gemm_store(
    const float* __restrict__ x,
    const __bf16* __restrict__ wht,
    const float* __restrict__ bias, float* __restrict__ out0) {
  __shared__ __align__(16) __bf16 As[2][BM * BK];  // 2 x 8 KB
  __shared__ __align__(16) __bf16 Bs[2][BN * BK];  // 2 x 16 KB
  float* Ebuf = reinterpret_cast<float*>(&Bs[0][0]);  // 32 KB store buffer

  const int tid  = threadIdx.x;
  const int lane = tid & 63;
  const int wave = tid >> 6;
  const int wr   = wave >> 2;      // 0..1 (M, 64 rows each)
  const int wc   = wave & 3;       // 0..3 (N, 64 cols each)
  const int fr   = lane & 15;
  const int q4   = lane >> 4;
  const int prot8 = ((q4 + ((fr >> 1) & 3)) & 3) * 8;  // verified conflict-free

  // XCD swizzle: 1024 blocks; each XCD owns 8 row-panels x 16 col-panels
  const int bx  = blockIdx.x;
  const int xcd = bx & 7;
  const int ii  = bx >> 3;         // 0..127
  const int tn  = ii >> 3;         // 0..15
  const int tm  = xcd * 8 + (ii & 7);  // 0..63
  const int row0 = tm * BM;
  const int col0 = tn * BN;

  const int r0 = tid >> 2;                               // 0..127
  const int l8 = (((tid & 3) - ((tid >> 3) & 3)) & 3) * 8;

  const float*  Axf = x   + (size_t)row0 * D_DIM;
  const __bf16* Bsc = wht + (size_t)col0 * D_DIM;

  f32x4 a0_, a1_;   // in-flight A (f32, pre-cvt)

#define ALOAD(t_)                                                            \
  do {                                                                       \
    const size_t o_ = (size_t)r0 * D_DIM + (t_) * 32 + l8;                   \
    a0_ = *reinterpret_cast<const f32x4*>(Axf + o_);                         \
    a1_ = *reinterpret_cast<const f32x4*>(Axf + o_ + 4);                     \
  } while (0)

#define CVTW(b)                                                              \
  do {                                                                       \
    bf16x8 h_;                                                               \
    h_[0] = (__bf16)a0_[0]; h_[1] = (__bf16)a0_[1];                          \
    h_[2] = (__bf16)a0_[2]; h_[3] = (__bf16)a0_[3];                          \
    h_[4] = (__bf16)a1_[0]; h_[5] = (__bf16)a1_[1];                          \
    h_[6] = (__bf16)a1_[2]; h_[7] = (__bf16)a1_[3];                          \
    *reinterpret_cast<bf16x8*>(&As[b][tid * 8]) = h_;                        \
  } while (0)

#define BGLD(b, t_)                                                          \
  do {                                                                       \
    const int ko_ = (t_) * 32;                                               \
    gld_lds16(Bsc + (size_t)r0 * D_DIM + ko_ + l8, &Bs[b][tid * 8]);         \
    gld_lds16(Bsc + (size_t)(128 + r0) * D_DIM + ko_ + l8,                   \
              &Bs[b][(512 + tid) * 8]);                                      \
  } while (0)

#define COMPUTE(b)                                                           \
  {                                                                          \
    bf16x8 bfr_[4];                                                          \
    _Pragma("unroll")                                                        \
    for (int n = 0; n < 4; ++n)                                              \
      bfr_[n] = *reinterpret_cast<const bf16x8*>(                            \
          &Bs[b][(wc * 64 + n * 16 + fr) * BK + prot8]);                     \
    __builtin_amdgcn_s_setprio(1);                                           \
    _Pragma("unroll")                                                        \
    for (int m = 0; m < 4; ++m) {                                            \
      const bf16x8 av_ = *reinterpret_cast<const bf16x8*>(                   \
          &As[b][(wr * 64 + m * 16 + fr) * BK + prot8]);                     \
      _Pragma("unroll")                                                      \
      for (int n = 0; n < 4; ++n)                                            \
        acc[m][n] = MFMA(bfr_[n], av_, acc[m][n]);                           \
    }                                                                        \
    __builtin_amdgcn_s_setprio(0);                                           \
  }

  f32x4 acc[4][4];
#pragma unroll
  for (int m = 0; m < 4; ++m)
#pragma unroll
    for (int n = 0; n < 4; ++n) acc[m][n] = (f32x4){0.f, 0.f, 0.f, 0.f};

  ALOAD(0);
  BGLD(0, 0);
  CVTW(0);
  __syncthreads();

#pragma unroll 1
  for (int it = 0; it < 15; ++it) {
    ALOAD(2 * it + 1); BGLD(1, 2 * it + 1);
    COMPUTE(0)
    CVTW(1);
    __syncthreads();
    ALOAD(2 * it + 2); BGLD(0, 2 * it + 2);
    COMPUTE(1)
    CVTW(0);
    __syncthreads();
  }
  ALOAD(31); BGLD(1, 31);
  COMPUTE(0)
  CVTW(1);
  __syncthreads();
  COMPUTE(1)

  // ---- store-only epilogue: LDS transpose -> bias -> contiguous stores ----
  const int tcol = tid & 63;            // 16B col-chunk within 256-col tile
  const int gcol = col0 + tcol * 4;
  const f32x4 bias4 = *reinterpret_cast<const f32x4*>(bias + gcol);

#pragma unroll
  for (int ck = 0; ck < 4; ++ck) {
    __syncthreads();
    if (wr == (ck >> 1)) {
#pragma unroll
      for (int mi = 0; mi < 2; ++mi) {
        const int lrow = mi * 16 + fr;          // 0..31
        const int m = (ck & 1) * 2 + mi;
#pragma unroll
        for (int n = 0; n < 4; ++n) {
          const int s = (wc * 16 + n * 4 + q4) ^ (lrow & 7);  // 16B slot 0..63
          *reinterpret_cast<f32x4*>(&Ebuf[lrow * 256 + s * 4]) = acc[m][n];
        }
      }
    }
    __syncthreads();
#pragma unroll
    for (int rr = 0; rr < 4; ++rr) {
      const int lrow = rr * 8 + wave;           // 0..31
      const int grow = row0 + ck * 32 + lrow;
      const f32x4 a = *reinterpret_cast<const f32x4*>(
          &Ebuf[lrow * 256 + (tcol ^ (lrow & 7)) * 4]);
      // NORMAL store (not nt): out0 lands in L2/L3 for act_kernel's re-read
      *reinterpret_cast<f32x4*>(out0 + (size_t)grow * N_DIM + gcol) = a + bias4;
    }
  }
}

// ---------------------------------------------------------------------------
// act_kernel: streaming activation. 1 thread = one 16-wide segment (64 B
// contiguous; wave = 4 KB contiguous). In-thread softmax (no shuffles).
// out0 read (L3-resident), gumbel nt-load, out1 nt-store. High occupancy
// (~50 VGPR) -> HBM-rate streaming, overlapped across the whole device.
__global__ __launch_bounds__(256) void act_kernel(
    const float* __restrict__ o0, const float* __restrict__ gumbel,
    const int* __restrict__ flags, float* __restrict__ out1) {
  const int sid = blockIdx.x * 256 + threadIdx.x;       // segment id
  const int flag = flags[sid & 255];                     // seg-in-row
  const size_t base = (size_t)sid * 16;

  f32x4 o[4];
#pragma unroll
  for (int i = 0; i < 4; ++i)
    o[i] = *reinterpret_cast<const f32x4*>(o0 + base + i * 4);

  f32x4 v[4];
  if (flag == 0) {
#pragma unroll
    for (int i = 0; i < 4; ++i)
#pragma unroll
      for (int z = 0; z < 4; ++z) {
        const float c = fminf(fmaxf(o[i][z], -15.f), 15.f);
        const float e = __expf(2.f * c);
        v[i][z] = (e - 1.f) * fast_rcp(e + 1.f);
      }
  } else {
    f32x4 t[4];
    float mx = -3.4e38f;
#pragma unroll
    for (int i = 0; i < 4; ++i) {
      const f32x4 g = __builtin_nontemporal_load(
          reinterpret_cast<const f32x4*>(gumbel + base + i * 4));
#pragma unroll
      for (int z = 0; z < 4; ++z) {
        t[i][z] = (o[i][z] + g[z]) * TAU_INV;
        mx = fmaxf(mx, t[i][z]);
      }
    }
    float s = 0.f;
#pragma unroll
    for (int i = 0; i < 4; ++i)
#pragma unroll
      for (int z = 0; z < 4; ++z) {
        t[i][z] = __expf(t[i][z] - mx);
        s += t[i][z];
      }
    const float inv = fast_rcp(s);
#pragma unroll
    for (int i = 0; i < 4; ++i)
#pragma unroll
      for (int z = 0; z < 4; ++z) v[i][z] = t[i][z] * inv;
  }
#pragma unroll
  for (int i = 0; i < 4; ++i)
    __builtin_nontemporal_store(v[i],
        reinterpret_cast<f32x4*>(out1 + base + i * 4));
}

// ---------------------------------------------------------------------------
// fallback (only if ws_size too small): naive but correct
__global__ void fallback_kernel(const float* __restrict__ x, const float* __restrict__ W,
                                const float* __restrict__ bias, const float* __restrict__ gumbel,
                                const int* __restrict__ flags, float* __restrict__ out) {
  const size_t idx = (size_t)blockIdx.x * blockDim.x + threadIdx.x;
  const int row = (int)(idx / N_DIM);
  const int col = (int)(idx % N_DIM);
  float o = bias[col];
  const float* xr = x + (size_t)row * D_DIM;
  for (int k = 0; k < D_DIM; ++k) o += xr[k] * W[(size_t)k * N_DIM + col];
  out[idx] = o;
  float v;
  if (flags[col >> 4] == 0) {
    const float oc = fminf(fmaxf(o, -15.f), 15.f);
    const float e2 = __expf(2.f * oc);
    v = (e2 - 1.f) / (e2 + 1.f);
  } else {
    const float t = (o + gumbel[idx]) * TAU_INV;
    float mx = t;
    mx = fmaxf(mx, __shfl_xor(mx, 1));
    mx = fmaxf(mx, __shfl_xor(mx, 2));
    mx = fmaxf(mx, __shfl_xor(mx, 4));
    mx = fmaxf(mx, __shfl_xor(mx, 8));
    float e = __expf(t - mx);
    float ssum = e;
    ssum += __shfl_xor(ssum, 1);
    ssum += __shfl_xor(ssum, 2);
    ssum += __shfl_xor(ssum, 4);
    ssum += __shfl_xor(ssum, 8);
    v = e / ssum;
  }
  out[(size_t)B_DIM * N_DIM + idx] = v;
}

// ---------------------------------------------------------------------------
extern "C" void kernel_launch(void* const* d_in, const int* in_sizes, int n_in,
                              void* d_out, int out_size, void* d_ws, size_t ws_size,
                              hipStream_t stream) {
  const float* x      = (const float*)d_in[0];
  const float* W      = (const float*)d_in[1];
  const float* bias   = (const float*)d_in[2];
  const float* gumbel = (const float*)d_in[3];
  const int*   flags  = (const int*)d_in[4];
  float* out = (float*)d_out;

  const size_t wcnt = (size_t)N_DIM * D_DIM;
  const size_t need = wcnt * sizeof(__bf16);  // ~8 MB

  if (ws_size < need) {
    const long long nblocks = (long long)B_DIM * N_DIM / 256;
    fallback_kernel<<<(int)nblocks, 256, 0, stream>>>(x, W, bias, gumbel, flags, out);
    return;
  }

  __bf16* wht = (__bf16*)d_ws;
  float* out0 = out;
  float* out1 = out + (size_t)B_DIM * N_DIM;

  prep_w<<<(N_DIM / 32) * (D_DIM / 32), 256, 0, stream>>>(W, wht);
  gemm_store<<<(B_DIM / BM) * (N_DIM / BN), THREADS, 0, stream>>>(
      x, wht, bias, out0);
  act_kernel<<<(B_DIM * (N_DIM / 16)) / 256, 256, 0, stream>>>(
      out0, gumbel, flags, out1);
}